// Round 7
// baseline (277.896 us; speedup 1.0000x reference)
//
#include <hip/hip_runtime.h>

#define NLINKS 4096
#define VEC 16            // fvec4 chunks per lane: 16 * 4 * 64 lanes = 4096

typedef float fvec4 __attribute__((ext_vector_type(4)));

constexpr float kPmax = 0.1f;
constexpr float kBudget = 100.0f;
constexpr int kGrid = 7;           // fixed tau grid over [0.56, 0.72]
constexpr int kFallbackIters = 10; // Illinois iters when tau outside the grid

// clip(x,0,PMAX) in ONE VALU op: v_med3_f32
__device__ __forceinline__ float clip01(float x) {
  return __builtin_amdgcn_fmed3f(x, 0.0f, kPmax);
}

// Batched reduce: N independent sums share interleaved shuffle latency.
template <int N>
__device__ __forceinline__ void waveReduceSumN(float* x) {
#pragma unroll
  for (int m = 32; m >= 1; m >>= 1) {
    float t[N];
#pragma unroll
    for (int k = 0; k < N; ++k) t[k] = __shfl_xor(x[k], m, 64);
#pragma unroll
    for (int k = 0; k < N; ++k) x[k] += t[k];
  }
}
__device__ __forceinline__ float waveReduceMax(float x) {
#pragma unroll
  for (int m = 32; m >= 1; m >>= 1) x = fmaxf(x, __shfl_xor(x, m, 64));
  return x;
}

// Fused, STREAMING design. History:
//  R3/R5: register-resident row => 128 VGPR, 4 waves/SIMD, occupancy 16%,
//         HBM 29%, VALU 27% -> latency-bound at 87 us.
//  R6: two-kernel split => cross-XCD L2 misses + launch gap, regressed.
// Here: row is never register-resident (VGPR<=64, 8 waves/SIMD); passes 2/3
// re-read the row from L3 (same wave -> same XCD; 128 MiB input < 256 MiB L3).
__global__ __launch_bounds__(256, 8) void proj_kernel(
    const float* __restrict__ raw, float* __restrict__ out, int rows) {
  const int wave = threadIdx.x >> 6;
  const int lane = threadIdx.x & 63;
  const int row = blockIdx.x * 4 + wave;
  if (row >= rows) return;

  const fvec4* rp = (const fvec4*)(raw + (size_t)row * NLINKS);
  fvec4* op = (fvec4*)(out + (size_t)row * NLINKS);

  // tau grid: rows ~N(0,1), n=4096 => tau* = 0.641 +- 0.019 (1 sigma).
  // [0.56,0.72] covers +-4 sigma; outside -> Illinois fallback (cache-warm).
  const float pts[kGrid] = {0.56f, 0.59f, 0.615f, 0.64f, 0.665f, 0.69f, 0.72f};

  // ---- Pass 1 (HBM stream): fs=g(0), g(pts[i]), row max. ----
  float mx = -1e30f;
  float s[kGrid + 1];
#pragma unroll
  for (int k = 0; k <= kGrid; ++k) s[k] = 0.f;
#pragma unroll
  for (int j = 0; j < VEC; ++j) {
    const fvec4 x4 = rp[lane + 64 * j];  // cached: passes 2/3 re-read via L3
#pragma unroll
    for (int c = 0; c < 4; ++c) {
      const float x = x4[c];
      mx = fmaxf(mx, x);
      s[0] += clip01(x);
#pragma unroll
      for (int i = 0; i < kGrid; ++i) s[i + 1] += clip01(x - pts[i]);
    }
  }
  waveReduceSumN<kGrid + 1>(s);
  mx = waveReduceMax(mx);

  float tau = 0.0f;  // feasible rows keep tau=0 -> pass 3 emits clip(x)
  if (s[0] > kBudget) {
    float a, ga, b, gb;
    bool need_iter = false;
    if (s[1] < kBudget) {                 // tau < pts[0]: wide segment
      a = 0.f; ga = s[0]; b = pts[0]; gb = s[1]; need_iter = true;
    } else if (s[kGrid] > kBudget) {      // tau > pts[last]: wide segment
      a = pts[kGrid - 1]; ga = s[kGrid]; b = mx; gb = 0.f; need_iter = true;
    } else {
      a = pts[0]; ga = s[1]; b = pts[1]; gb = s[2];
#pragma unroll
      for (int i = 1; i < kGrid - 1; ++i) {
        if (s[i + 1] >= kBudget && s[i + 2] <= kBudget) {
          a = pts[i]; ga = s[i + 1]; b = pts[i + 1]; gb = s[i + 2];
        }
      }
    }

    if (need_iter) {  // rare: Illinois false position, row is cache-warm
      int side = 0;
#pragma unroll 1
      for (int it = 0; it < kFallbackIters; ++it) {
        const float denom = gb - ga;
        float t = (denom != 0.f) ? b - (gb - kBudget) * (b - a) / denom
                                 : 0.5f * (a + b);
        if (!(t > a && t < b)) t = 0.5f * (a + b);
        float g = 0.f;
#pragma unroll 1
        for (int j = 0; j < VEC; ++j) {
          const fvec4 x4 = rp[lane + 64 * j];
          g += clip01(x4.x - t) + clip01(x4.y - t) +
               clip01(x4.z - t) + clip01(x4.w - t);
        }
        waveReduceSumN<1>(&g);
        if (g > kBudget) {
          a = t; ga = g;
          if (side == 1) gb = kBudget + 0.5f * (gb - kBudget);
          side = 1;
        } else {
          b = t; gb = g;
          if (side == -1) ga = kBudget + 0.5f * (ga - kBudget);
          side = -1;
        }
      }
    }

    // Secant within the bracketed segment.
    const float dd = ga - gb;
    float tau0 = (dd != 0.f) ? a + (ga - kBudget) * (b - a) / dd : 0.5f * (a + b);
    if (!(tau0 >= a && tau0 <= b)) tau0 = 0.5f * (a + b);

    // ---- Pass 2 (L3-warm): Newton correction, matches reference. ----
    float gn[2] = {0.f, 0.f};  // g(tau0), n_active
#pragma unroll 1
    for (int j = 0; j < VEC; ++j) {
      const fvec4 x4 = rp[lane + 64 * j];
#pragma unroll
      for (int c = 0; c < 4; ++c) {
        const float t = x4[c] - tau0;
        gn[0] += clip01(t);
        gn[1] += (t > 0.f && t < kPmax) ? 1.f : 0.f;
      }
    }
    waveReduceSumN<2>(gn);
    tau = tau0 + (gn[0] - kBudget) / fmaxf(gn[1], 1.0f);
  }

  // ---- Pass 3 (L3-warm read, nt store): out = clip(x - tau). ----
#pragma unroll 1
  for (int j = 0; j < VEC; ++j) {
    const fvec4 x4 = rp[lane + 64 * j];
    fvec4 o;
#pragma unroll
    for (int c = 0; c < 4; ++c) o[c] = clip01(x4[c] - tau);
    __builtin_nontemporal_store(o, &op[lane + 64 * j]);
  }
}

extern "C" void kernel_launch(void* const* d_in, const int* in_sizes, int n_in,
                              void* d_out, int out_size, void* d_ws, size_t ws_size,
                              hipStream_t stream) {
  const float* raw = (const float*)d_in[0];
  float* out = (float*)d_out;
  const int rows = in_sizes[0] / NLINKS;
  hipLaunchKernelGGL(proj_kernel, dim3((rows + 3) / 4), dim3(256), 0, stream,
                     raw, out, rows);
}

// Round 8
// 230.921 us; speedup vs baseline: 1.2034x; 1.2034x over previous
//
#include <hip/hip_runtime.h>

#define NLINKS 4096

typedef float fvec4 __attribute__((ext_vector_type(4)));

constexpr float kPmax = 0.1f;
constexpr float kBudget = 100.0f;
constexpr int kGrid = 7;           // fixed tau grid over [0.56, 0.72]
constexpr int kFallbackIters = 10; // Illinois iters when tau outside the grid

// clip(x,0,PMAX) in ONE VALU op: v_med3_f32
__device__ __forceinline__ float clip01(float x) {
  return __builtin_amdgcn_fmed3f(x, 0.0f, kPmax);
}

// Batched reduce: N independent sums share interleaved shuffle latency.
template <int N>
__device__ __forceinline__ void waveReduceSumN(float* x) {
#pragma unroll
  for (int m = 32; m >= 1; m >>= 1) {
    float t[N];
#pragma unroll
    for (int k = 0; k < N; ++k) t[k] = __shfl_xor(x[k], m, 64);
#pragma unroll
    for (int k = 0; k < N; ++k) x[k] += t[k];
  }
}
__device__ __forceinline__ float waveReduceMax(float x) {
#pragma unroll
  for (int m = 32; m >= 1; m >>= 1) x = fmaxf(x, __shfl_xor(x, m, 64));
  return x;
}

// Design constraints proven by earlier rounds:
//  - touch the row from global EXACTLY once (R7: re-read passes hit HBM,
//    FETCH 1.5x input, 124 us);
//  - don't make the row wave-register-resident (R3/R5: 64 data VGPRs ->
//    spill or 4 waves/SIMD, latency-bound at 87 us);
//  - stay fused (R6: kernel split loses XCD locality, regressed).
// => block-per-row, row distributed over 256 threads (16 floats/thread,
//    ~48 VGPR total, 8 waves/SIMD), block reduces via tiny LDS scratch.
__global__ __launch_bounds__(256, 8) void proj_kernel(
    const float* __restrict__ raw, float* __restrict__ out, int rows) {
  __shared__ float red[4][kGrid + 2];  // per-wave partials: 8 sums + max
  __shared__ float red2[4][2];         // newton / fallback partials

  const int row = blockIdx.x;
  const int t = threadIdx.x;
  const int wave = t >> 6;
  const int lane = t & 63;

  const fvec4* rp = (const fvec4*)(raw + (size_t)row * NLINKS);
  fvec4* op = (fvec4*)(out + (size_t)row * NLINKS);

  // tau grid: rows ~N(0,1), n=4096 => tau* = 0.641 +- 0.019 (1 sigma).
  // [0.56,0.72] covers +-4 sigma; outside -> Illinois fallback (register data).
  const float pts[kGrid] = {0.56f, 0.59f, 0.615f, 0.64f, 0.665f, 0.69f, 0.72f};

  // ONE global read: 4 fvec4/thread, stride-256 (perfectly coalesced).
  fvec4 v[4];
#pragma unroll
  for (int j = 0; j < 4; ++j) v[j] = rp[t + 256 * j];

  // Stats over this thread's 16 elements: g(0), g(pts[i]), max.
  float mx = -1e30f;
  float s[kGrid + 1];
#pragma unroll
  for (int k = 0; k <= kGrid; ++k) s[k] = 0.f;
#pragma unroll
  for (int j = 0; j < 4; ++j) {
#pragma unroll
    for (int c = 0; c < 4; ++c) {
      const float x = v[j][c];
      mx = fmaxf(mx, x);
      s[0] += clip01(x);
#pragma unroll
      for (int i = 0; i < kGrid; ++i) s[i + 1] += clip01(x - pts[i]);
    }
  }
  waveReduceSumN<kGrid + 1>(s);
  mx = waveReduceMax(mx);
  if (lane == 0) {
#pragma unroll
    for (int k = 0; k <= kGrid; ++k) red[wave][k] = s[k];
    red[wave][kGrid + 1] = mx;
  }
  __syncthreads();
  // All threads form identical block totals from LDS (uniform -> no bcast).
  float tot[kGrid + 1];
#pragma unroll
  for (int k = 0; k <= kGrid; ++k)
    tot[k] = (red[0][k] + red[1][k]) + (red[2][k] + red[3][k]);
  const float mxt = fmaxf(fmaxf(red[0][kGrid + 1], red[1][kGrid + 1]),
                          fmaxf(red[2][kGrid + 1], red[3][kGrid + 1]));

  float tau = 0.0f;  // feasible rows keep tau=0 -> emit clip(x)
  if (tot[0] > kBudget) {  // block-uniform branch (syncs inside are safe)
    float a, ga, b, gb;
    bool need_iter = false;
    if (tot[1] < kBudget) {               // tau < pts[0]: wide segment
      a = 0.f; ga = tot[0]; b = pts[0]; gb = tot[1]; need_iter = true;
    } else if (tot[kGrid] > kBudget) {    // tau > pts[last]: wide segment
      a = pts[kGrid - 1]; ga = tot[kGrid]; b = mxt; gb = 0.f; need_iter = true;
    } else {
      a = pts[0]; ga = tot[1]; b = pts[1]; gb = tot[2];
#pragma unroll
      for (int i = 1; i < kGrid - 1; ++i) {
        if (tot[i + 1] >= kBudget && tot[i + 2] <= kBudget) {
          a = pts[i]; ga = tot[i + 1]; b = pts[i + 1]; gb = tot[i + 2];
        }
      }
    }

    if (need_iter) {  // rare; g(t) evals use register data + block reduce
      int side = 0;
      for (int it = 0; it < kFallbackIters; ++it) {
        const float denom = gb - ga;
        float tt = (denom != 0.f) ? b - (gb - kBudget) * (b - a) / denom
                                  : 0.5f * (a + b);
        if (!(tt > a && tt < b)) tt = 0.5f * (a + b);
        float g = 0.f;
#pragma unroll
        for (int j = 0; j < 4; ++j)
          g += clip01(v[j].x - tt) + clip01(v[j].y - tt) +
               clip01(v[j].z - tt) + clip01(v[j].w - tt);
        waveReduceSumN<1>(&g);
        __syncthreads();  // protect red2 reuse across iterations
        if (lane == 0) red2[wave][0] = g;
        __syncthreads();
        g = (red2[0][0] + red2[1][0]) + (red2[2][0] + red2[3][0]);
        if (g > kBudget) {
          a = tt; ga = g;
          if (side == 1) gb = kBudget + 0.5f * (gb - kBudget);
          side = 1;
        } else {
          b = tt; gb = g;
          if (side == -1) ga = kBudget + 0.5f * (ga - kBudget);
          side = -1;
        }
      }
    }

    // Secant within the bracketed segment (uniform across block).
    const float dd = ga - gb;
    float tau0 = (dd != 0.f) ? a + (ga - kBudget) * (b - a) / dd
                             : 0.5f * (a + b);
    if (!(tau0 >= a && tau0 <= b)) tau0 = 0.5f * (a + b);

    // Newton correction from registers (matches reference semantics).
    float gn[2] = {0.f, 0.f};  // g(tau0), n_active
#pragma unroll
    for (int j = 0; j < 4; ++j) {
#pragma unroll
      for (int c = 0; c < 4; ++c) {
        const float d = v[j][c] - tau0;
        gn[0] += clip01(d);
        gn[1] += (d > 0.f && d < kPmax) ? 1.f : 0.f;
      }
    }
    waveReduceSumN<2>(gn);
    __syncthreads();
    if (lane == 0) { red2[wave][0] = gn[0]; red2[wave][1] = gn[1]; }
    __syncthreads();
    const float gsum = (red2[0][0] + red2[1][0]) + (red2[2][0] + red2[3][0]);
    const float nact = (red2[0][1] + red2[1][1]) + (red2[2][1] + red2[3][1]);
    tau = tau0 + (gsum - kBudget) / fmaxf(nact, 1.0f);
  }

  // ONE global write: out = clip(x - tau), nt stores (never re-read).
#pragma unroll
  for (int j = 0; j < 4; ++j) {
    fvec4 o;
#pragma unroll
    for (int c = 0; c < 4; ++c) o[c] = clip01(v[j][c] - tau);
    __builtin_nontemporal_store(o, &op[t + 256 * j]);
  }
}

extern "C" void kernel_launch(void* const* d_in, const int* in_sizes, int n_in,
                              void* d_out, int out_size, void* d_ws, size_t ws_size,
                              hipStream_t stream) {
  const float* raw = (const float*)d_in[0];
  float* out = (float*)d_out;
  const int rows = in_sizes[0] / NLINKS;
  hipLaunchKernelGGL(proj_kernel, dim3(rows), dim3(256), 0, stream,
                     raw, out, rows);
}